// Round 14
// baseline (326.140 us; speedup 1.0000x reference)
//
#include <hip/hip_runtime.h>
#include <hip/hip_bf16.h>

// Linear attention (Shen 2018), B=2, N=16384, D=512, H=8, DK=64.
// Round 14 = R13 with the VGPR-squeeze spill fixed:
//   - phase1 pinned with amdgpu_waves_per_eu(4,4): launch_bounds' 2nd arg is
//     only a MIN; the compiler squeezed to 64 VGPR (8 waves/EU) and spilled
//     ~30 regs (R13: VGPR_Count=64, +52MB scratch writes). Pinning max=4
//     removes the incentive -> full 128-reg budget, no spill.
//   - K and V B-panel quarters loaded together before the K-MFMA cluster so
//     V-panel L2 latency hides under K MFMAs.
// Everything else byte-identical to R13 (verified, absmax 1.9e-5).

using u16 = unsigned short;
typedef __attribute__((ext_vector_type(8))) short bf16x8;
typedef __attribute__((ext_vector_type(4))) float f32x4;

#define D_MODEL 512
#define SEQ 16384

// SWZ fragment layout for a 512x512 bf16 operand consumed as mfma_16x16x32
// row-panels: element (col,k) at cb16=col>>4, lc=col&15, ksm=k>>5, g=(k>>3)&3,
// j=k&7, lane=g*16+lc:  idx = cb16*8192 + ksm*512 + lane*8 + j   (u16 units)

// ---- ws layout (bytes) ----
#define PART_OFF 0u            // f32 [16 bh][128 grp][64 e][64 d] = 33,554,432
#define SUMS_OFF 33554432u     // f32 [16 bh][128 grp][64 d]       = 524,288
#define CTX_OFF  34078720u     // f32 [16][64 d][64 e]             = 262,144
#define WTKS_OFF 34340864u     // bf16 swz 512x512 = 524,288
#define WTVS_OFF 34865152u
#define WTQS_OFF 35389440u
#define MTS_OFF  35913728u     // bf16 swz [2]x512x512 = 1,048,576
#define WS_NEEDED 36962304u

__device__ __forceinline__ float bf2f(u16 u) {
  union { unsigned int i; float f; } x; x.i = ((unsigned int)u) << 16; return x.f;
}
__device__ __forceinline__ u16 f2bf(float f) {
  union { float ff; unsigned int i; } x; x.ff = f;
  unsigned int r = x.i + 0x7fffu + ((x.i >> 16) & 1u);  // RNE
  return (u16)(r >> 16);
}
__device__ __forceinline__ unsigned int pk2(float lo, float hi) {
  union { __hip_bfloat162 h; unsigned int u; } x;
  x.h = __float22bfloat162_rn(float2{lo, hi});
  return x.u;
}
__device__ __forceinline__ bf16x8 ldsrd(const u16* base, int row, int rowbytes,
                                        int kbyte, int mask) {
  return *(const bf16x8*)((const char*)base + row * rowbytes + (kbyte ^ ((row & mask) << 4)));
}
// LDS-only barrier (no vmcnt drain): safe because at every barrier the only
// in-flight vmem ops are register-destined loads or fire-and-forget stores.
__device__ __forceinline__ void bar_lgkm() {
  asm volatile("s_waitcnt lgkmcnt(0)" ::: "memory");
  __builtin_amdgcn_sched_barrier(0);
  __builtin_amdgcn_s_barrier();
  __builtin_amdgcn_sched_barrier(0);
}

// ------- transpose+convert W -> swizzled fragment-order bf16 panels ---------
__launch_bounds__(256)
__global__ void wcvt_kernel(const float* __restrict__ Wk, const float* __restrict__ Wv,
                            const float* __restrict__ Wq, u16* __restrict__ WTks,
                            u16* __restrict__ WTvs, u16* __restrict__ WTqs) {
  const float* in = blockIdx.z == 0 ? Wk : (blockIdx.z == 1 ? Wv : Wq);
  u16* out = blockIdx.z == 0 ? WTks : (blockIdx.z == 1 ? WTvs : WTqs);
  __shared__ float S[64][65];  // [k][col]
  const int t = threadIdx.x;
  const int k0 = blockIdx.y << 6, c0 = blockIdx.x << 6;
#pragma unroll
  for (int ii = 0; ii < 4; ++ii) {
    const int idx = t + ii * 256;
    const int r = idx >> 4, c4 = (idx & 15) << 2;
    const float4 v = *(const float4*)(in + (k0 + r) * D_MODEL + c0 + c4);
    S[r][c4] = v.x; S[r][c4 + 1] = v.y; S[r][c4 + 2] = v.z; S[r][c4 + 3] = v.w;
  }
  __syncthreads();
#pragma unroll
  for (int it = 0; it < 2; ++it) {
    const int fi = it * 256 + t;             // 0..511
    const int cb_loc = fi >> 7;              // 0..3
    const int ksm_loc = (fi >> 6) & 1;       // 0..1
    const int lane = fi & 63;
    const int col_loc = cb_loc * 16 + (lane & 15);
    const int kl0 = ksm_loc * 32 + (lane >> 4) * 8;
    union { bf16x8 v; u16 e[8]; } o;
#pragma unroll
    for (int jj = 0; jj < 8; ++jj) o.e[jj] = f2bf(S[kl0 + jj][col_loc]);
    const int cb16 = blockIdx.x * 4 + cb_loc;
    const int ksm = blockIdx.y * 2 + ksm_loc;
    *(bf16x8*)(out + cb16 * 8192 + ksm * 512 + lane * 8) = o.v;
  }
}

// ---------------- phase 1: k-quartered T14 pipeline, 32KB LDS ---------------
// grid 1024: xc=f&7 (XCD), k=f>>3: rowgroup = xc*32 + (k>>2) in [0,256),
// hp = k&3. Block: 8 waves = 2 heads (hloc=w>>2) x 4 col-quarters (cq=w&3);
// 4 chunks of 32 rows; per chunk 4 k-quarters staged [32][128] each.
__global__ void
__launch_bounds__(512)
__attribute__((amdgpu_waves_per_eu(4, 4)))
phase1_kernel(const float* __restrict__ key, const float* __restrict__ value,
              const u16* __restrict__ WTks, const u16* __restrict__ WTvs,
              const float* __restrict__ bkp, const float* __restrict__ bvp,
              float* __restrict__ part, float* __restrict__ sums) {
  __shared__ __align__(16) u16 smem[16384];  // 32KB
  u16* KA = smem;            // [32 n][256B] swz mask 7 (8KB)
  u16* VA = smem + 4096;     // (8KB)
  u16* ET = smem + 8192;     // [2 hloc][64 d][64B] swz mask 3 (8KB)
  u16* VT = smem + 12288;    // (8KB)
  const int t = threadIdx.x;
  const int lane = t & 63, w = t >> 6;
  const int g = lane >> 4, lc = lane & 15;
  const int f = blockIdx.x;
  const int xc = f & 7, kk2 = f >> 3;
  const int rowgroup = xc * 32 + (kk2 >> 2);   // 0..255
  const int hp = kk2 & 3;
  const int hloc = w >> 2, cq = w & 3;
  const int h = hp * 2 + hloc;
  const int dl = cq * 16 + lc;
  const int b = rowgroup >> 7, grpl = rowgroup & 127;
  const int bh = b * 8 + h;
  u16* ETh = ET + hloc * 2048;
  u16* VTh = VT + hloc * 2048;
  const u16* wtkb = WTks + (h * 4 + cq) * 8192;
  const u16* wtvb = WTvs + (h * 4 + cq) * 8192;
  const float bbk = bkp[h * 64 + dl];
  const float bbv = bvp[h * 64 + dl];
  const int sr = t >> 4;                 // staging row 0..31
  const int so8 = t & 15;                // staging col-octet
  const int swoff = sr * 256 + ((so8 * 16) ^ ((sr & 7) << 4));

  f32x4 pacc[4];
#pragma unroll
  for (int em = 0; em < 4; ++em) pacc[em] = (f32x4){0.f, 0.f, 0.f, 0.f};
  float sp = 0.f;

  // T14 in-flight staging registers
  float4 kr0, kr1, vr0, vr1;
  auto ISSUE = [&](int ci, int kq) {
    const int n0 = (rowgroup * 4 + ci) * 32;
    const float* kp = key + (size_t)(n0 + sr) * D_MODEL + kq * 128 + so8 * 8;
    kr0 = *(const float4*)kp; kr1 = *(const float4*)(kp + 4);
    const float* vp = value + (size_t)(n0 + sr) * D_MODEL + kq * 128 + so8 * 8;
    vr0 = *(const float4*)vp; vr1 = *(const float4*)(vp + 4);
  };

  ISSUE(0, 0);  // prologue

#pragma unroll 1
  for (int ci = 0; ci < 4; ++ci) {
    f32x4 aK0 = (f32x4){0.f,0.f,0.f,0.f}, aK1 = aK0, aV0 = aK0, aV1 = aK0;

#pragma unroll
    for (int kq = 0; kq < 4; ++kq) {
      bar_lgkm();   // prior consumers of KA/VA (and ET/VT at chunk start) done
      // ---- write staged quarter (compiler inserts vmcnt wait on kr/vr) ----
      {
        uint4 wk; wk.x = pk2(kr0.x, kr0.y); wk.y = pk2(kr0.z, kr0.w);
        wk.z = pk2(kr1.x, kr1.y); wk.w = pk2(kr1.z, kr1.w);
        *(uint4*)((char*)KA + swoff) = wk;
        uint4 wv; wv.x = pk2(vr0.x, vr0.y); wv.y = pk2(vr0.z, vr0.w);
        wv.z = pk2(vr1.x, vr1.y); wv.w = pk2(vr1.z, vr1.w);
        *(uint4*)((char*)VA + swoff) = wv;
      }
      // ---- T14: issue NEXT quarter's loads now; they fly across barriers --
      if (!(ci == 3 && kq == 3)) ISSUE(kq == 3 ? ci + 1 : ci, (kq + 1) & 3);
      // ---- B panels for K AND V issued together (V latency hides under K) -
      bf16x8 bK[4], bV[4];
#pragma unroll
      for (int ksl = 0; ksl < 4; ++ksl)
        bK[ksl] = *(const bf16x8*)(wtkb + (kq * 4 + ksl) * 512 + lane * 8);
#pragma unroll
      for (int ksl = 0; ksl < 4; ++ksl)
        bV[ksl] = *(const bf16x8*)(wtvb + (kq * 4 + ksl) * 512 + lane * 8);
      bar_lgkm();   // staged quarter visible
      // ---- K quarter-GEMM ----
#pragma unroll
      for (int ksl = 0; ksl < 4; ++ksl) {
        const int kb = ksl * 64 + g * 16;
        bf16x8 a0 = ldsrd(KA, lc, 256, kb, 7);
        bf16x8 a1 = ldsrd(KA, 16 + lc, 256, kb, 7);
        aK0 = __builtin_amdgcn_mfma_f32_16x16x32_bf16(a0, bK[ksl], aK0, 0, 0, 0);
        aK1 = __builtin_amdgcn_mfma_f32_16x16x32_bf16(a1, bK[ksl], aK1, 0, 0, 0);
      }
      // ---- V quarter-GEMM ----
#pragma unroll
      for (int ksl = 0; ksl < 4; ++ksl) {
        const int kb = ksl * 64 + g * 16;
        bf16x8 a0 = ldsrd(VA, lc, 256, kb, 7);
        bf16x8 a1 = ldsrd(VA, 16 + lc, 256, kb, 7);
        aV0 = __builtin_amdgcn_mfma_f32_16x16x32_bf16(a0, bV[ksl], aV0, 0, 0, 0);
        aV1 = __builtin_amdgcn_mfma_f32_16x16x32_bf16(a1, bV[ksl], aV1, 0, 0, 0);
      }
    }

    // ---- E epilogue: exp, colsum accumulate, E^T strip -> ETh ----
    {
#pragma unroll
      for (int r = 0; r < 4; ++r) { aK0[r] = __expf(aK0[r] + bbk); sp += aK0[r]; }
#pragma unroll
      for (int r = 0; r < 4; ++r) { aK1[r] = __expf(aK1[r] + bbk); sp += aK1[r]; }
      *(uint2*)((char*)ETh + dl * 64 + ((g * 8) ^ ((dl & 3) << 4))) =
          make_uint2(pk2(aK0[0], aK0[1]), pk2(aK0[2], aK0[3]));
      *(uint2*)((char*)ETh + dl * 64 + ((32 + g * 8) ^ ((dl & 3) << 4))) =
          make_uint2(pk2(aK1[0], aK1[1]), pk2(aK1[2], aK1[3]));
    }
    // ---- V epilogue: bias, V^T strip -> VTh ----
    *(uint2*)((char*)VTh + dl * 64 + ((g * 8) ^ ((dl & 3) << 4))) =
        make_uint2(pk2(aV0[0] + bbv, aV0[1] + bbv), pk2(aV0[2] + bbv, aV0[3] + bbv));
    *(uint2*)((char*)VTh + dl * 64 + ((32 + g * 8) ^ ((dl & 3) << 4))) =
        make_uint2(pk2(aV1[0] + bbv, aV1[1] + bbv), pk2(aV1[2] + bbv, aV1[3] + bbv));
    bar_lgkm();  // ET/VT complete across the head's 4 waves

    // ---- partial E^T V (k = 32 rows) accumulated into pacc ----
    {
      bf16x8 paf = ldsrd(ETh, dl, 64, g * 16, 3);
#pragma unroll
      for (int em = 0; em < 4; ++em) {
        bf16x8 pbf = ldsrd(VTh, em * 16 + lc, 64, g * 16, 3);
        pacc[em] = __builtin_amdgcn_mfma_f32_16x16x32_bf16(paf, pbf, pacc[em], 0, 0, 0);
      }
    }
    // loop-top bar_lgkm covers: partial's ET/VT reads done before next
    // epilogue writes; KA/VA reads done before next staging write.
  }

  // ---- one store per block: f32 partials [e][d] + colsums ----
  float* pp = part + (size_t)(bh * 128 + grpl) * 4096;
#pragma unroll
  for (int em = 0; em < 4; ++em)
    *(f32x4*)(pp + (em * 16 + lc) * 64 + cq * 16 + g * 4) = pacc[em];
  sp += __shfl_xor(sp, 16); sp += __shfl_xor(sp, 32);
  if (g == 0) sums[(size_t)(bh * 128 + grpl) * 64 + dl] = sp;
}

// ---------------- phase 2: reduce partials -> ctx[d][e] ---------------------
__launch_bounds__(256)
__global__ void reduce_kernel(const float* __restrict__ part, const float* __restrict__ sums,
                              float* __restrict__ ctx) {
  __shared__ float den[64];
  const int bh = blockIdx.x;
  const int t = threadIdx.x;
  if (t < 64) {
    float s = 0.f;
    for (int gp = 0; gp < 128; ++gp) s += sums[(size_t)(bh * 128 + gp) * 64 + t];
    den[t] = s;
  }
  float4 A0 = {0,0,0,0}, A1 = {0,0,0,0}, A2 = {0,0,0,0}, A3 = {0,0,0,0};
  const float* pb = part + (size_t)bh * 128 * 4096;
  for (int gp = 0; gp < 128; ++gp) {
    const float4* q = (const float4*)(pb + gp * 4096 + t * 16);
    const float4 q0 = q[0], q1 = q[1], q2 = q[2], q3 = q[3];
    A0.x += q0.x; A0.y += q0.y; A0.z += q0.z; A0.w += q0.w;
    A1.x += q1.x; A1.y += q1.y; A1.z += q1.z; A1.w += q1.w;
    A2.x += q2.x; A2.y += q2.y; A2.z += q2.z; A2.w += q2.w;
    A3.x += q3.x; A3.y += q3.y; A3.z += q3.z; A3.w += q3.w;
  }
  __syncthreads();
  // positions p = t*16 + i in [e][d]: e = t>>2, d = (t&3)*16 + i
  const int e = t >> 2, d0 = (t & 3) * 16;
  float* cb = ctx + (size_t)bh * 4096 + e;
  const float r0[4] = {A0.x, A0.y, A0.z, A0.w};
  const float r1[4] = {A1.x, A1.y, A1.z, A1.w};
  const float r2[4] = {A2.x, A2.y, A2.z, A2.w};
  const float r3[4] = {A3.x, A3.y, A3.z, A3.w};
#pragma unroll
  for (int i = 0; i < 4; ++i) cb[(d0 + i) * 64] = r0[i] / den[d0 + i];
#pragma unroll
  for (int i = 0; i < 4; ++i) cb[(d0 + 4 + i) * 64] = r1[i] / den[d0 + 4 + i];
#pragma unroll
  for (int i = 0; i < 4; ++i) cb[(d0 + 8 + i) * 64] = r2[i] / den[d0 + 8 + i];
#pragma unroll
  for (int i = 0; i < 4; ++i) cb[(d0 + 12 + i) * 64] = r3[i] / den[d0 + 12 + i];
}

// -------- MTs (swizzled) = (ctx_h @ Wo_h)^T per batch -----------------------
__launch_bounds__(256)
__global__ void mbigT_kernel(const float* __restrict__ ctx, const float* __restrict__ Wo,
                             u16* __restrict__ MTs) {
  __shared__ float Clds[64][65];
  __shared__ float Wlds2[64][64];
  const int t = threadIdx.x;
  const int tx = t & 15, ty = t >> 4;
  const int cc = blockIdx.x;
  const int bh = blockIdx.y;
  const int b = bh >> 3, h = bh & 7;
  const float* ch = ctx + bh * 4096;
  for (int i4 = t; i4 < 1024; i4 += 256) {
    const int r = i4 >> 4, c = (i4 & 15) << 2;
    const float4 v = *(const float4*)(ch + (r << 6) + c);
    Clds[r][c] = v.x; Clds[r][c + 1] = v.y; Clds[r][c + 2] = v.z; Clds[r][c + 3] = v.w;
    const float4 wv = *(const float4*)(Wo + (h * 64 + r) * D_MODEL + cc * 64 + c);
    Wlds2[r][c] = wv.x; Wlds2[r][c + 1] = wv.y; Wlds2[r][c + 2] = wv.z; Wlds2[r][c + 3] = wv.w;
  }
  __syncthreads();
  float acc[4][4] = {};
#pragma unroll 8
  for (int k = 0; k < 64; ++k) {
    float a[4], wv[4];
#pragma unroll
    for (int i = 0; i < 4; ++i) a[i] = Clds[(ty << 2) + i][k];
#pragma unroll
    for (int j = 0; j < 4; ++j) wv[j] = Wlds2[k][(tx << 2) + j];
#pragma unroll
    for (int i = 0; i < 4; ++i)
#pragma unroll
      for (int j = 0; j < 4; ++j) acc[i][j] = fmaf(a[i], wv[j], acc[i][j]);
  }
  // scattered swizzled-layout stores (tiny kernel)
#pragma unroll
  for (int i = 0; i < 4; ++i)
#pragma unroll
    for (int j = 0; j < 4; ++j) {
      const int c = cc * 64 + (tx << 2) + j;      // out col
      const int k = h * 64 + (ty << 2) + i;       // k dim
      const int cb16 = c >> 4, lcc = c & 15;
      const int ksm = k >> 5, gg = (k >> 3) & 3, jb = k & 7;
      MTs[(size_t)b * 262144 + cb16 * 8192 + ksm * 512 + (gg * 16 + lcc) * 8 + jb]
          = f2bf(acc[i][j]);
    }
}

// ---------------- phase 3: Q pipeline + softmax + out-GEMM ------------------
__launch_bounds__(512, 2)
__global__ void phase3_kernel(const float* __restrict__ query, const u16* __restrict__ WTqs,
                              const float* __restrict__ bqp, const u16* __restrict__ MTs,
                              const float* __restrict__ bop, float* __restrict__ out) {
  __shared__ __align__(16) u16 smem[20480];  // 40KB
  u16* SL = smem;          // [2][2048] Q slices
  u16* P  = smem + 4096;   // [32 n][512 d], rows 1024B, swz mask 7
  const int t = threadIdx.x;
  const int lane = t & 63, w = t >> 6;
  const int g = lane >> 4, lc = lane & 15;
  const int chunk = blockIdx.x;
  const int n0 = chunk * 32;
  const int b = chunk >> 9;
  const int c0 = w * 64;
  const int srow = t >> 4;
  const int scol = (t & 15) << 2;
  const int sbyte = srow * 128 + (((t & 15) << 3) ^ ((srow & 7) << 4));
  const float* qbase = query + (size_t)(n0 + srow) * D_MODEL + scol;

  float4 lq[2];
  f32x4 acc[4][2];
#pragma unroll
  for (int m = 0; m < 4; ++m)
#pragma unroll
    for (int n = 0; n < 2; ++n) acc[m][n] = (f32x4){0.f, 0.f, 0.f, 0.f};

  lq[0] = *(const float4*)(qbase);
  lq[1] = *(const float4*)(qbase + 64);
  *(uint2*)((char*)SL + sbyte) = make_uint2(pk2(lq[0].x, lq[0].y), pk2(lq[0].z, lq[0].w));
  bar_lgkm();

#pragma unroll
  for (int ks = 0; ks < 8; ++ks) {
    if (ks + 2 < 8) lq[ks & 1] = *(const float4*)(qbase + (ks + 2) * 64);
    if (ks + 1 < 8) {
      const int p = (ks + 1) & 1;
      *(uint2*)((char*)SL + p * 4096 + sbyte) =
          make_uint2(pk2(lq[p].x, lq[p].y), pk2(lq[p].z, lq[p].w));
    }
    const u16* S = SL + (ks & 1) * 2048;
#pragma unroll
    for (int kk = 0; kk < 2; ++kk) {
      const int ksm = ks * 2 + kk;
      bf16x8 af[4], bfr[2];
#pragma unroll
      for (int mf = 0; mf < 4; ++mf)
        af[mf] = *(const bf16x8*)(WTqs + (w * 4 + mf) * 8192 + ksm * 512 + lane * 8);
#pragma unroll
      for (int nf = 0; nf < 2; ++nf) bfr[nf] = ldsrd(S, nf * 16 + lc, 128, kk * 64 + g * 16, 7);
#pragma unroll
      for (int mf = 0; mf < 4; ++mf)
#pragma unroll
        for (int nf = 0; nf < 2; ++nf)
          acc[mf][nf] = __builtin_amdgcn_mfma_f32_16x16x32_bf16(af[mf], bfr[nf], acc[mf][nf], 0, 0, 0);
    }
    bar_lgkm();
  }
  // ---- softmax over d (per n), *1/8, bf16 -> P ----
  {
    float bqv[4][4];
#pragma unroll
    for (int m = 0; m < 4; ++m)
#pragma unroll
      for (int r = 0; r < 4; ++r) bqv[m][r] = bqp[c0 + m * 16 + g * 4 + r];
#pragma unroll
    for (int nf = 0; nf < 2; ++nf) {
      float mx = -3.0e38f;
#pragma unroll
      for (int m = 0; m < 4; ++m)
#pragma unroll
        for (int r = 0; r < 4; ++r) {
          const float v = acc[m][nf][r] + bqv[m][r];
          acc[m][nf][r] = v; mx = fmaxf(mx, v);
        }
      mx = fmaxf(mx, __shfl_xor(mx, 16)); mx = fmaxf(mx, __shfl_xor(mx, 32));
      float s = 0.f;
#pragma unroll
      for (int m = 0; m < 4; ++m)
#pragma unroll
        for (int r = 0; r < 4; ++r) {
          const float e = __expf(acc[m][nf][r] - mx);
          acc[m][nf][r] = e; s += e;
        }
      s += __shfl_xor(s, 16); s += __shfl_xor(s, 32);
      const float fsc = 0.125f / s;
      const int n = nf * 16 + lc;
#pragma unroll
      for (int m = 0; m < 4; ++m) {
        const uint2 pw = make_uint2(pk2(acc[m][nf][0] * fsc, acc[m][nf][1] * fsc),
                                    pk2(acc[m][nf][2] * fsc, acc[m][nf][3] * fsc));
        *(uint2*)((char*)P + n * 1024 + ((w * 128 + m * 32 + g * 8) ^ ((n & 7) << 4))) = pw;
      }
    }
  }
  bar_lgkm();
  // ---- out^T = Mbig^T[b] @ P^T ----
  f32x4 oc[4][2];
#pragma unroll
  for (int m = 0; m < 4; ++m)
#pragma unroll
    for (int n = 0; n < 2; ++n) oc[m][n] = (f32x4){0.f, 0.f, 0.f, 0.f};
  const u16* MT = MTs + (size_t)b * 262144;
#pragma unroll 2
  for (int ks = 0; ks < 16; ++ks) {
    bf16x8 af[4], bfr[2];
#pragma unroll
    for (int mf = 0; mf < 4; ++mf)
      af[mf] = *(const bf16x8*)(MT + (w * 4 + mf) * 8192 + ks * 512 + lane * 8);
#pragma unroll
    for (int nf = 0; nf < 2; ++nf) bfr[nf] = ldsrd(P, nf * 16 + lc, 1024, ks * 64 + g * 16, 7);
#pragma unroll
    for (int mf = 0; mf < 4; ++mf)
#pragma unroll
      for (int nf = 0; nf < 2; ++nf)
        oc[mf][nf] = __builtin_amdgcn_mfma_f32_16x16x32_bf16(af[mf], bfr[nf], oc[mf][nf], 0, 0, 0);
  }
  {
    float bov[4][4];
#pragma unroll
    for (int m = 0; m < 4; ++m)
#pragma unroll
      for (int r = 0; r < 4; ++r) bov[m][r] = bop[c0 + m * 16 + g * 4 + r];
#pragma unroll
    for (int mf = 0; mf < 4; ++mf)
#pragma unroll
      for (int nf = 0; nf < 2; ++nf) {
        float4 o;
        o.x = oc[mf][nf][0] + bov[mf][0]; o.y = oc[mf][nf][1] + bov[mf][1];
        o.z = oc[mf][nf][2] + bov[mf][2]; o.w = oc[mf][nf][3] + bov[mf][3];
        *(float4*)(out + (size_t)(n0 + nf * 16 + lc) * D_MODEL + c0 + mf * 16 + g * 4) = o;
      }
  }
}

__global__ void sentinel_kernel(float* out) { out[0] = 1.0e9f; }

extern "C" void kernel_launch(void* const* d_in, const int* in_sizes, int n_in,
                              void* d_out, int out_size, void* d_ws, size_t ws_size,
                              hipStream_t stream) {
  const float* query = (const float*)d_in[0];
  const float* key   = (const float*)d_in[1];
  const float* value = (const float*)d_in[2];
  const float* Wq = (const float*)d_in[3];
  const float* bq = (const float*)d_in[4];
  const float* Wk = (const float*)d_in[5];
  const float* bk = (const float*)d_in[6];
  const float* Wv = (const float*)d_in[7];
  const float* bv = (const float*)d_in[8];
  const float* Wo = (const float*)d_in[9];
  const float* bo = (const float*)d_in[10];
  float* out = (float*)d_out;
  char* ws = (char*)d_ws;

  if (ws_size < (size_t)WS_NEEDED) {
    sentinel_kernel<<<1, 1, 0, stream>>>(out);
    return;
  }

  float* part = (float*)(ws + PART_OFF);
  float* sums = (float*)(ws + SUMS_OFF);
  float* ctx  = (float*)(ws + CTX_OFF);
  u16* WTks   = (u16*)(ws + WTKS_OFF);
  u16* WTvs   = (u16*)(ws + WTVS_OFF);
  u16* WTqs   = (u16*)(ws + WTQS_OFF);
  u16* MTs    = (u16*)(ws + MTS_OFF);

  const dim3 blk256(256);
  wcvt_kernel<<<dim3(8, 8, 3), blk256, 0, stream>>>(Wk, Wv, Wq, WTks, WTvs, WTqs);
  phase1_kernel<<<1024, 512, 0, stream>>>(key, value, WTks, WTvs, bk, bv, part, sums);
  reduce_kernel<<<16, blk256, 0, stream>>>(part, sums, ctx);
  mbigT_kernel<<<dim3(8, 16), blk256, 0, stream>>>(ctx, Wo, MTs);
  phase3_kernel<<<1024, 512, 0, stream>>>(query, WTqs, bq, MTs, bo, out);
}

// Round 15
// 272.057 us; speedup vs baseline: 1.1988x; 1.1988x over previous
//
#include <hip/hip_runtime.h>
#include <hip/hip_bf16.h>

// Linear attention (Shen 2018), B=2, N=16384, D=512, H=8, DK=64.
// Round 15: phase1 rebuilt as a phase3 clone after diagnosing the R11-R14
// VGPR trap: __launch_bounds__' 2nd arg is MIN waves/EU -> (512,4) CAPS
// VGPRs at 64 and forced spills (R13/R14: VGPR=64 + 50-190MB scratch).
//   - phase1 now __launch_bounds__(512,2) (R7-verified: ~120 regs, no spill)
//   - double-buffered [32][64] K/V slices, dist-2 register prefetch,
//     ONE bar_lgkm per slice (phase3's proven schedule), 32KB LDS
//   - chunk-end exp/transpose/partial epilogue byte-identical to R13
// reduce/mbigT/phase3/wcvt unchanged (verified, absmax 1.9e-5).

using u16 = unsigned short;
typedef __attribute__((ext_vector_type(8))) short bf16x8;
typedef __attribute__((ext_vector_type(4))) float f32x4;

#define D_MODEL 512
#define SEQ 16384

// SWZ fragment layout for a 512x512 bf16 operand consumed as mfma_16x16x32
// row-panels: element (col,k) at cb16=col>>4, lc=col&15, ksm=k>>5, g=(k>>3)&3,
// j=k&7, lane=g*16+lc:  idx = cb16*8192 + ksm*512 + lane*8 + j   (u16 units)

// ---- ws layout (bytes) ----
#define PART_OFF 0u            // f32 [16 bh][128 grp][64 e][64 d] = 33,554,432
#define SUMS_OFF 33554432u     // f32 [16 bh][128 grp][64 d]       = 524,288
#define CTX_OFF  34078720u     // f32 [16][64 d][64 e]             = 262,144
#define WTKS_OFF 34340864u     // bf16 swz 512x512 = 524,288
#define WTVS_OFF 34865152u
#define WTQS_OFF 35389440u
#define MTS_OFF  35913728u     // bf16 swz [2]x512x512 = 1,048,576
#define WS_NEEDED 36962304u

__device__ __forceinline__ float bf2f(u16 u) {
  union { unsigned int i; float f; } x; x.i = ((unsigned int)u) << 16; return x.f;
}
__device__ __forceinline__ u16 f2bf(float f) {
  union { float ff; unsigned int i; } x; x.ff = f;
  unsigned int r = x.i + 0x7fffu + ((x.i >> 16) & 1u);  // RNE
  return (u16)(r >> 16);
}
__device__ __forceinline__ unsigned int pk2(float lo, float hi) {
  union { __hip_bfloat162 h; unsigned int u; } x;
  x.h = __float22bfloat162_rn(float2{lo, hi});
  return x.u;
}
__device__ __forceinline__ bf16x8 ldsrd(const u16* base, int row, int rowbytes,
                                        int kbyte, int mask) {
  return *(const bf16x8*)((const char*)base + row * rowbytes + (kbyte ^ ((row & mask) << 4)));
}
// LDS-only barrier (no vmcnt drain): safe because at every barrier the only
// in-flight vmem ops are register-destined loads or fire-and-forget stores.
__device__ __forceinline__ void bar_lgkm() {
  asm volatile("s_waitcnt lgkmcnt(0)" ::: "memory");
  __builtin_amdgcn_sched_barrier(0);
  __builtin_amdgcn_s_barrier();
  __builtin_amdgcn_sched_barrier(0);
}

// ------- transpose+convert W -> swizzled fragment-order bf16 panels ---------
__launch_bounds__(256)
__global__ void wcvt_kernel(const float* __restrict__ Wk, const float* __restrict__ Wv,
                            const float* __restrict__ Wq, u16* __restrict__ WTks,
                            u16* __restrict__ WTvs, u16* __restrict__ WTqs) {
  const float* in = blockIdx.z == 0 ? Wk : (blockIdx.z == 1 ? Wv : Wq);
  u16* out = blockIdx.z == 0 ? WTks : (blockIdx.z == 1 ? WTvs : WTqs);
  __shared__ float S[64][65];  // [k][col]
  const int t = threadIdx.x;
  const int k0 = blockIdx.y << 6, c0 = blockIdx.x << 6;
#pragma unroll
  for (int ii = 0; ii < 4; ++ii) {
    const int idx = t + ii * 256;
    const int r = idx >> 4, c4 = (idx & 15) << 2;
    const float4 v = *(const float4*)(in + (k0 + r) * D_MODEL + c0 + c4);
    S[r][c4] = v.x; S[r][c4 + 1] = v.y; S[r][c4 + 2] = v.z; S[r][c4 + 3] = v.w;
  }
  __syncthreads();
#pragma unroll
  for (int it = 0; it < 2; ++it) {
    const int fi = it * 256 + t;             // 0..511
    const int cb_loc = fi >> 7;              // 0..3
    const int ksm_loc = (fi >> 6) & 1;       // 0..1
    const int lane = fi & 63;
    const int col_loc = cb_loc * 16 + (lane & 15);
    const int kl0 = ksm_loc * 32 + (lane >> 4) * 8;
    union { bf16x8 v; u16 e[8]; } o;
#pragma unroll
    for (int jj = 0; jj < 8; ++jj) o.e[jj] = f2bf(S[kl0 + jj][col_loc]);
    const int cb16 = blockIdx.x * 4 + cb_loc;
    const int ksm = blockIdx.y * 2 + ksm_loc;
    *(bf16x8*)(out + cb16 * 8192 + ksm * 512 + lane * 8) = o.v;
  }
}

// ---------------- phase 1: phase3-style dbuf slice pipeline -----------------
// grid 1024: xc=f&7 (XCD), k=f>>3: rowgroup = xc*32 + (k>>2) in [0,256),
// hp = k&3. Block: 8 waves = 2 heads (hloc=w>>2) x 4 col-quarters (cq=w&3);
// 4 chunks of 32 rows = 32 slices of [32 rows][64 k], double-buffered.
__launch_bounds__(512, 2)
__global__ void phase1_kernel(const float* __restrict__ key, const float* __restrict__ value,
                              const u16* __restrict__ WTks, const u16* __restrict__ WTvs,
                              const float* __restrict__ bkp, const float* __restrict__ bvp,
                              float* __restrict__ part, float* __restrict__ sums) {
  __shared__ __align__(16) u16 smem[16384];  // 32KB
  u16* KA = smem;            // [2 buf][32 n][64 k], rows 128B, swz mask 7 (8KB)
  u16* VA = smem + 4096;     // same (8KB)
  u16* ET = smem + 8192;     // [2 hloc][64 d][32 n], rows 64B, swz mask 3 (8KB)
  u16* VT = smem + 12288;    // (8KB)
  const int t = threadIdx.x;
  const int lane = t & 63, w = t >> 6;
  const int g = lane >> 4, lc = lane & 15;
  const int f = blockIdx.x;
  const int xc = f & 7, kk2 = f >> 3;
  const int rowgroup = xc * 32 + (kk2 >> 2);   // 0..255
  const int hp = kk2 & 3;
  const int hloc = w >> 2, cq = w & 3;
  const int h = hp * 2 + hloc;
  const int dl = cq * 16 + lc;
  const int b = rowgroup >> 7, grpl = rowgroup & 127;
  const int bh = b * 8 + h;
  u16* ETh = ET + hloc * 2048;
  u16* VTh = VT + hloc * 2048;
  const u16* wtkb = WTks + (h * 4 + cq) * 8192;
  const u16* wtvb = WTvs + (h * 4 + cq) * 8192;
  const float bbk = bkp[h * 64 + dl];
  const float bbv = bvp[h * 64 + dl];
  const int sr = t >> 4;                 // staging row 0..31
  const int sc = t & 15;                 // staging col-quad (4 f32 / 4 bf16*2)
  const int sbyte = sr * 128 + ((sc << 3) ^ ((sr & 7) << 4));

  f32x4 pacc[4];
#pragma unroll
  for (int em = 0; em < 4; ++em) pacc[em] = (f32x4){0.f, 0.f, 0.f, 0.f};
  float sp = 0.f;
  f32x4 aK0 = (f32x4){0.f,0.f,0.f,0.f}, aK1 = aK0, aV0 = aK0, aV1 = aK0;

  float4 kreg[2], vreg[2];   // dist-2 slice prefetch (set = slice & 1)
  auto LOADSL = [&](int set, int gs) {
    const int row = (rowgroup * 4 + (gs >> 3)) * 32 + sr;
    const float* kp = key + (size_t)row * D_MODEL + (gs & 7) * 64 + sc * 4;
    kreg[set] = *(const float4*)kp;
    const float* vp = value + (size_t)row * D_MODEL + (gs & 7) * 64 + sc * 4;
    vreg[set] = *(const float4*)vp;
  };
  auto WRITESL = [&](int set) {
    *(uint2*)((char*)(KA + set * 2048) + sbyte) =
        make_uint2(pk2(kreg[set].x, kreg[set].y), pk2(kreg[set].z, kreg[set].w));
    *(uint2*)((char*)(VA + set * 2048) + sbyte) =
        make_uint2(pk2(vreg[set].x, vreg[set].y), pk2(vreg[set].z, vreg[set].w));
  };

  // prologue: slices 0,1 in regs; slice 0 -> buf0
  LOADSL(0, 0);
  LOADSL(1, 1);
  WRITESL(0);
  bar_lgkm();

#pragma unroll 1
  for (int ci = 0; ci < 4; ++ci) {
#pragma unroll
    for (int ks = 0; ks < 8; ++ks) {
      const int gs = ci * 8 + ks;
      // dist-2 prefetch: slice gs+2 into set (gs&1) (its slice was written
      // to LDS last iteration); write slice gs+1 to the opposite buffer.
      if (gs + 2 < 32) LOADSL(gs & 1, gs + 2);
      if (gs + 1 < 32) WRITESL((gs + 1) & 1);
      const u16* bufK = KA + (gs & 1) * 2048;
      const u16* bufV = VA + (gs & 1) * 2048;
#pragma unroll
      for (int kk = 0; kk < 2; ++kk) {
        const int ksm = ks * 2 + kk;
        const bf16x8 bK = *(const bf16x8*)(wtkb + ksm * 512 + lane * 8);
        const bf16x8 bV = *(const bf16x8*)(wtvb + ksm * 512 + lane * 8);
        const int kb = kk * 64 + g * 16;
        bf16x8 a0 = ldsrd(bufK, lc, 128, kb, 7);
        bf16x8 a1 = ldsrd(bufK, 16 + lc, 128, kb, 7);
        aK0 = __builtin_amdgcn_mfma_f32_16x16x32_bf16(a0, bK, aK0, 0, 0, 0);
        aK1 = __builtin_amdgcn_mfma_f32_16x16x32_bf16(a1, bK, aK1, 0, 0, 0);
        bf16x8 c0 = ldsrd(bufV, lc, 128, kb, 7);
        bf16x8 c1 = ldsrd(bufV, 16 + lc, 128, kb, 7);
        aV0 = __builtin_amdgcn_mfma_f32_16x16x32_bf16(c0, bV, aV0, 0, 0, 0);
        aV1 = __builtin_amdgcn_mfma_f32_16x16x32_bf16(c1, bV, aV1, 0, 0, 0);
      }
      if (ks == 7) {
        // ---- chunk epilogue (byte-identical math to R13, verified) ----
        // E: exp, colsum accumulate, E^T strip -> ETh
#pragma unroll
        for (int r = 0; r < 4; ++r) { aK0[r] = __expf(aK0[r] + bbk); sp += aK0[r]; }
#pragma unroll
        for (int r = 0; r < 4; ++r) { aK1[r] = __expf(aK1[r] + bbk); sp += aK1[r]; }
        *(uint2*)((char*)ETh + dl * 64 + ((g * 8) ^ ((dl & 3) << 4))) =
            make_uint2(pk2(aK0[0], aK0[1]), pk2(aK0[2], aK0[3]));
        *(uint2*)((char*)ETh + dl * 64 + ((32 + g * 8) ^ ((dl & 3) << 4))) =
            make_uint2(pk2(aK1[0], aK1[1]), pk2(aK1[2], aK1[3]));
        // V: bias, V^T strip -> VTh
        *(uint2*)((char*)VTh + dl * 64 + ((g * 8) ^ ((dl & 3) << 4))) =
            make_uint2(pk2(aV0[0] + bbv, aV0[1] + bbv), pk2(aV0[2] + bbv, aV0[3] + bbv));
        *(uint2*)((char*)VTh + dl * 64 + ((32 + g * 8) ^ ((dl & 3) << 4))) =
            make_uint2(pk2(aV1[0] + bbv, aV1[1] + bbv), pk2(aV1[2] + bbv, aV1[3] + bbv));
        bar_lgkm();  // ET/VT complete across the head's 4 waves
        // partial E^T V (k = 32 rows) accumulated into pacc
        {
          bf16x8 paf = ldsrd(ETh, dl, 64, g * 16, 3);
#pragma unroll
          for (int em = 0; em < 4; ++em) {
            bf16x8 pbf = ldsrd(VTh, em * 16 + lc, 64, g * 16, 3);
            pacc[em] = __builtin_amdgcn_mfma_f32_16x16x32_bf16(paf, pbf, pacc[em], 0, 0, 0);
          }
        }
        aK0 = (f32x4){0.f,0.f,0.f,0.f}; aK1 = aK0; aV0 = aK0; aV1 = aK0;
      }
      bar_lgkm();  // slice gs+1 visible; buf (gs&1) reads done; (chunk end:
                   // partial's ET/VT reads done before next epilogue writes)
    }
  }

  // ---- one store per block: f32 partials [e][d] + colsums ----
  float* pp = part + (size_t)(bh * 128 + grpl) * 4096;
#pragma unroll
  for (int em = 0; em < 4; ++em)
    *(f32x4*)(pp + (em * 16 + lc) * 64 + cq * 16 + g * 4) = pacc[em];
  sp += __shfl_xor(sp, 16); sp += __shfl_xor(sp, 32);
  if (g == 0) sums[(size_t)(bh * 128 + grpl) * 64 + dl] = sp;
}

// ---------------- phase 2: reduce partials -> ctx[d][e] ---------------------
__launch_bounds__(256)
__global__ void reduce_kernel(const float* __restrict__ part, const float* __restrict__ sums,
                              float* __restrict__ ctx) {
  __shared__ float den[64];
  const int bh = blockIdx.x;
  const int t = threadIdx.x;
  if (t < 64) {
    float s = 0.f;
    for (int gp = 0; gp < 128; ++gp) s += sums[(size_t)(bh * 128 + gp) * 64 + t];
    den[t] = s;
  }
  float4 A0 = {0,0,0,0}, A1 = {0,0,0,0}, A2 = {0,0,0,0}, A3 = {0,0,0,0};
  const float* pb = part + (size_t)bh * 128 * 4096;
  for (int gp = 0; gp < 128; ++gp) {
    const float4* q = (const float4*)(pb + gp * 4096 + t * 16);
    const float4 q0 = q[0], q1 = q[1], q2 = q[2], q3 = q[3];
    A0.x += q0.x; A0.y += q0.y; A0.z += q0.z; A0.w += q0.w;
    A1.x += q1.x; A1.y += q1.y; A1.z += q1.z; A1.w += q1.w;
    A2.x += q2.x; A2.y += q2.y; A2.z += q2.z; A2.w += q2.w;
    A3.x += q3.x; A3.y += q3.y; A3.z += q3.z; A3.w += q3.w;
  }
  __syncthreads();
  // positions p = t*16 + i in [e][d]: e = t>>2, d = (t&3)*16 + i
  const int e = t >> 2, d0 = (t & 3) * 16;
  float* cb = ctx + (size_t)bh * 4096 + e;
  const float r0[4] = {A0.x, A0.y, A0.z, A0.w};
  const float r1[4] = {A1.x, A1.y, A1.z, A1.w};
  const float r2[4] = {A2.x, A2.y, A2.z, A2.w};
  const float r3[4] = {A3.x, A3.y, A3.z, A3.w};
#pragma unroll
  for (int i = 0; i < 4; ++i) cb[(d0 + i) * 64] = r0[i] / den[d0 + i];
#pragma unroll
  for (int i = 0; i < 4; ++i) cb[(d0 + 4 + i) * 64] = r1[i] / den[d0 + 4 + i];
#pragma unroll
  for (int i = 0; i < 4; ++i) cb[(d0 + 8 + i) * 64] = r2[i] / den[d0 + 8 + i];
#pragma unroll
  for (int i = 0; i < 4; ++i) cb[(d0 + 12 + i) * 64] = r3[i] / den[d0 + 12 + i];
}

// -------- MTs (swizzled) = (ctx_h @ Wo_h)^T per batch -----------------------
__launch_bounds__(256)
__global__ void mbigT_kernel(const float* __restrict__ ctx, const float* __restrict__ Wo,
                             u16* __restrict__ MTs) {
  __shared__ float Clds[64][65];
  __shared__ float Wlds2[64][64];
  const int t = threadIdx.x;
  const int tx = t & 15, ty = t >> 4;
  const int cc = blockIdx.x;
  const int bh = blockIdx.y;
  const int b = bh >> 3, h = bh & 7;
  const float* ch = ctx + bh * 4096;
  for (int i4 = t; i4 < 1024; i4 += 256) {
    const int r = i4 >> 4, c = (i4 & 15) << 2;
    const float4 v = *(const float4*)(ch + (r << 6) + c);
    Clds[r][c] = v.x; Clds[r][c + 1] = v.y; Clds[r][c + 2] = v.z; Clds[r][c + 3] = v.w;
    const float4 wv = *(const float4*)(Wo + (h * 64 + r) * D_MODEL + cc * 64 + c);
    Wlds2[r][c] = wv.x; Wlds2[r][c + 1] = wv.y; Wlds2[r][c + 2] = wv.z; Wlds2[r][c + 3] = wv.w;
  }
  __syncthreads();
  float acc[4][4] = {};
#pragma unroll 8
  for (int k = 0; k < 64; ++k) {
    float a[4], wv[4];
#pragma unroll
    for (int i = 0; i < 4; ++i) a[i] = Clds[(ty << 2) + i][k];
#pragma unroll
    for (int j = 0; j < 4; ++j) wv[j] = Wlds2[k][(tx << 2) + j];
#pragma unroll
    for (int i = 0; i < 4; ++i)
#pragma unroll
      for (int j = 0; j < 4; ++j) acc[i][j] = fmaf(a[i], wv[j], acc[i][j]);
  }
  // scattered swizzled-layout stores (tiny kernel)
#pragma unroll
  for (int i = 0; i < 4; ++i)
#pragma unroll
    for (int j = 0; j < 4; ++j) {
      const int c = cc * 64 + (tx << 2) + j;      // out col
      const int k = h * 64 + (ty << 2) + i;       // k dim
      const int cb16 = c >> 4, lcc = c & 15;
      const int ksm = k >> 5, gg = (k >> 3) & 3, jb = k & 7;
      MTs[(size_t)b * 262144 + cb16 * 8192 + ksm * 512 + (gg * 16 + lcc) * 8 + jb]
          = f2bf(acc[i][j]);
    }
}

// ---------------- phase 3: Q pipeline + softmax + out-GEMM ------------------
__launch_bounds__(512, 2)
__global__ void phase3_kernel(const float* __restrict__ query, const u16* __restrict__ WTqs,
                              const float* __restrict__ bqp, const u16* __restrict__ MTs,
                              const float* __restrict__ bop, float* __restrict__ out) {
  __shared__ __align__(16) u16 smem[20480];  // 40KB
  u16* SL = smem;          // [2][2048] Q slices
  u16* P  = smem + 4096;   // [32 n][512 d], rows 1024B, swz mask 7
  const int t = threadIdx.x;
  const int lane = t & 63, w = t >> 6;
  const int g = lane >> 4, lc = lane & 15;
  const int chunk = blockIdx.x;
  const int n0 = chunk * 32;
  const int b = chunk >> 9;
  const int c0 = w * 64;
  const int srow = t >> 4;
  const int scol = (t & 15) << 2;
  const int sbyte = srow * 128 + (((t & 15) << 3) ^ ((srow & 7) << 4));
  const float* qbase = query + (size_t)(n0 + srow) * D_MODEL + scol;

  float4 lq[2];
  f32x4 acc[4][2];
#pragma unroll
  for (int m = 0; m < 4; ++m)
#pragma unroll
    for (int n = 0; n < 2; ++n) acc[m][n] = (f32x4){0.f, 0.f, 0.f, 0.f};

  lq[0] = *(const float4*)(qbase);
  lq[1] = *(const float4*)(qbase + 64);
  *(uint2*)((char*)SL + sbyte) = make_uint2(pk2(lq[0].x, lq[0].y), pk2(lq[0].z, lq[0].w));
  bar_lgkm();

#pragma unroll
  for (int ks = 0; ks < 8; ++ks) {
    if (ks + 2 < 8) lq[ks & 1] = *(const float4*)(qbase + (ks + 2) * 64);
    if (ks + 1 < 8) {
      const int p = (ks + 1) & 1;
      *(uint2*)((char*)SL + p * 4096 + sbyte) =
          make_uint2(pk2(lq[p].x, lq[p].y), pk2(lq[p].z, lq[p].w));
    }
    const u16* S = SL + (ks & 1) * 2048;
#pragma unroll
    for (int kk = 0; kk < 2; ++kk) {
      const int ksm = ks * 2 + kk;
      bf16x8 af[4], bfr[2];
#pragma unroll
      for (int mf = 0; mf < 4; ++mf)
        af[mf] = *(const bf16x8*)(WTqs + (w * 4 + mf) * 8192 + ksm * 512 + lane * 8);
#pragma unroll
      for (int nf = 0; nf < 2; ++nf) bfr[nf] = ldsrd(S, nf * 16 + lc, 128, kk * 64 + g * 16, 7);
#pragma unroll
      for (int mf = 0; mf < 4; ++mf)
#pragma unroll
        for (int nf = 0; nf < 2; ++nf)
          acc[mf][nf] = __builtin_amdgcn_mfma_f32_16x16x32_bf16(af[mf], bfr[nf], acc[mf][nf], 0, 0, 0);
    }
    bar_lgkm();
  }
  // ---- softmax over d (per n), *1/8, bf16 -> P ----
  {
    float bqv[4][4];
#pragma unroll
    for (int m = 0; m < 4; ++m)
#pragma unroll
      for (int r = 0; r < 4; ++r) bqv[m][r] = bqp[c0 + m * 16 + g * 4 + r];
#pragma unroll
    for (int nf = 0; nf < 2; ++nf) {
      float mx = -3.0e38f;
#pragma unroll
      for (int m = 0; m < 4; ++m)
#pragma unroll
        for (int r = 0; r < 4; ++r) {
          const float v = acc[m][nf][r] + bqv[m][r];
          acc[m][nf][r] = v; mx = fmaxf(mx, v);
        }
      mx = fmaxf(mx, __shfl_xor(mx, 16)); mx = fmaxf(mx, __shfl_xor(mx, 32));
      float s = 0.f;
#pragma unroll
      for (int m = 0; m < 4; ++m)
#pragma unroll
        for (int r = 0; r < 4; ++r) {
          const float e = __expf(acc[m][nf][r] - mx);
          acc[m][nf][r] = e; s += e;
        }
      s += __shfl_xor(s, 16); s += __shfl_xor(s, 32);
      const float fsc = 0.125f / s;
      const int n = nf * 16 + lc;
#pragma unroll
      for (int m = 0; m < 4; ++m) {
        const uint2 pw = make_uint2(pk2(acc[m][nf][0] * fsc, acc[m][nf][1] * fsc),
                                    pk2(acc[m][nf][2] * fsc, acc[m][nf][3] * fsc));
        *(uint2*)((char*)P + n * 1024 + ((w * 128 + m * 32 + g * 8) ^ ((n & 7) << 4))) = pw;
      }
    }
  }
  bar_lgkm();
  // ---- out^T = Mbig^T[b] @ P^T ----
  f32x4 oc[4][2];
#pragma unroll
  for (int m = 0; m < 4; ++m)
#pragma unroll
    for (int n = 0; n < 2; ++n) oc[m][n] = (f32x4){0.f, 0.f, 0.f, 0.f};
  const u16* MT = MTs + (size_t)b * 262144;
#pragma unroll 2
  for (int ks = 0; ks < 16; ++ks) {
    bf16x8 af[4], bfr[2];
#pragma unroll
    for (int mf = 0; mf < 4; ++mf)
      af[mf] = *(const bf16x8*)(MT + (w * 4 + mf) * 8192 + ks * 512 + lane * 8);
#pragma unroll
    for (int nf = 0; nf < 2; ++nf) bfr[nf] = ldsrd(P, nf * 16 + lc, 1024, ks * 64 + g * 16, 7);
#pragma unroll
    for (int mf = 0; mf < 4; ++mf)
#pragma unroll
      for (int nf = 0; nf < 2; ++nf)
        oc[mf][nf] = __builtin_amdgcn_mfma_f32_16x16x32_bf16(af[mf], bfr[nf], oc[mf][nf], 0, 0, 0);
  }
  {
    float bov[4][4];
#pragma unroll
    for (int m = 0; m < 4; ++m)
#pragma unroll
      for (int r = 0; r < 4; ++r) bov[m][r] = bop[c0 + m * 16 + g * 4 + r];
#pragma unroll
    for (int mf = 0; mf < 4; ++mf)
#pragma unroll
      for (int nf = 0; nf < 2; ++nf) {
        float4 o;
        o.x = oc[mf][nf][0] + bov[mf][0]; o.y = oc[mf][nf][1] + bov[mf][1];
        o.z = oc[mf][nf][2] + bov[mf][2]; o.w = oc[mf][nf][3] + bov[mf][3];
        *(float4*)(out + (size_t)(n0 + nf * 16 + lc) * D_MODEL + c0 + mf * 16 + g * 4) = o;
      }
  }
}

__global__ void sentinel_kernel(float* out) { out[0] = 1.0e9f; }

extern "C" void kernel_launch(void* const* d_in, const int* in_sizes, int n_in,
                              void* d_out, int out_size, void* d_ws, size_t ws_size,
                              hipStream_t stream) {
  const float* query = (const float*)d_in[0];
  const float* key   = (const float*)d_in[1];
  const float* value = (const float*)d_in[2];
  const float* Wq = (const float*)d_in[3];
  const float* bq = (const float*)d_in[4];
  const float* Wk = (const float*)d_in[5];
  const float* bk = (const float*)d_in[6];
  const float* Wv = (const float*)d_in[7];
  const float* bv = (const float*)d_in[8];
  const float* Wo = (const float*)d_in[9];
  const float* bo = (const float*)d_in[10];
  float* out = (float*)d_out;
  char* ws = (char*)d_ws;

  if (ws_size < (size_t)WS_NEEDED) {
    sentinel_kernel<<<1, 1, 0, stream>>>(out);
    return;
  }

  float* part = (float*)(ws + PART_OFF);
  float* sums = (float*)(ws + SUMS_OFF);
  float* ctx  = (float*)(ws + CTX_OFF);
  u16* WTks   = (u16*)(ws + WTKS_OFF);
  u16* WTvs   = (u16*)(ws + WTVS_OFF);
  u16* WTqs   = (u16*)(ws + WTQS_OFF);
  u16* MTs    = (u16*)(ws + MTS_OFF);

  const dim3 blk256(256);
  wcvt_kernel<<<dim3(8, 8, 3), blk256, 0, stream>>>(Wk, Wv, Wq, WTks, WTvs, WTqs);
  phase1_kernel<<<1024, 512, 0, stream>>>(key, value, WTks, WTvs, bk, bv, part, sums);
  reduce_kernel<<<16, blk256, 0, stream>>>(part, sums, ctx);
  mbigT_kernel<<<dim3(8, 16), blk256, 0, stream>>>(ctx, Wo, MTs);
  phase3_kernel<<<1024, 512, 0, stream>>>(query, WTqs, bq, MTs, bo, out);
}

// Round 16
// 214.885 us; speedup vs baseline: 1.5177x; 1.2661x over previous
//
#include <hip/hip_runtime.h>
#include <hip/hip_bf16.h>

// Linear attention (Shen 2018), B=2, N=16384, D=512, H=8, DK=64.
// Round 16: attack HBM-latency-boundedness (phase1 stuck ~160-180us across
// 7 structures; phase3 same disease at half the bytes):
//   - slices [32][64] -> [32][128]: half the barriers, 2x bytes per step
//   - depth-3 rotating register prefetch (fully unrolled => compile-time set
//     indices, no scratch): LDS-write waits on a load issued ~2 slice-periods
//     (>=900cyc) earlier -> vmcnt stall eliminated, 128-192B/thread in flight
//   - B-frag panels issued immediately after each barrier
// Epilogue/partial/reduce/mbigT math byte-identical to R15 (verified 1.9e-5).

using u16 = unsigned short;
typedef __attribute__((ext_vector_type(8))) short bf16x8;
typedef __attribute__((ext_vector_type(4))) float f32x4;

#define D_MODEL 512
#define SEQ 16384

// SWZ fragment layout for a 512x512 bf16 operand consumed as mfma_16x16x32
// row-panels: element (col,k) at cb16=col>>4, lc=col&15, ksm=k>>5, g=(k>>3)&3,
// j=k&7, lane=g*16+lc:  idx = cb16*8192 + ksm*512 + lane*8 + j   (u16 units)

// ---- ws layout (bytes) ----
#define PART_OFF 0u            // f32 [16 bh][128 grp][64 e][64 d] = 33,554,432
#define SUMS_OFF 33554432u     // f32 [16 bh][128 grp][64 d]       = 524,288
#define CTX_OFF  34078720u     // f32 [16][64 d][64 e]             = 262,144
#define WTKS_OFF 34340864u     // bf16 swz 512x512 = 524,288
#define WTVS_OFF 34865152u
#define WTQS_OFF 35389440u
#define MTS_OFF  35913728u     // bf16 swz [2]x512x512 = 1,048,576
#define WS_NEEDED 36962304u

__device__ __forceinline__ float bf2f(u16 u) {
  union { unsigned int i; float f; } x; x.i = ((unsigned int)u) << 16; return x.f;
}
__device__ __forceinline__ u16 f2bf(float f) {
  union { float ff; unsigned int i; } x; x.ff = f;
  unsigned int r = x.i + 0x7fffu + ((x.i >> 16) & 1u);  // RNE
  return (u16)(r >> 16);
}
__device__ __forceinline__ unsigned int pk2(float lo, float hi) {
  union { __hip_bfloat162 h; unsigned int u; } x;
  x.h = __float22bfloat162_rn(float2{lo, hi});
  return x.u;
}
__device__ __forceinline__ bf16x8 ldsrd(const u16* base, int row, int rowbytes,
                                        int kbyte, int mask) {
  return *(const bf16x8*)((const char*)base + row * rowbytes + (kbyte ^ ((row & mask) << 4)));
}
// LDS-only barrier (no vmcnt drain): safe because at every barrier the only
// in-flight vmem ops are register-destined loads or fire-and-forget stores.
__device__ __forceinline__ void bar_lgkm() {
  asm volatile("s_waitcnt lgkmcnt(0)" ::: "memory");
  __builtin_amdgcn_sched_barrier(0);
  __builtin_amdgcn_s_barrier();
  __builtin_amdgcn_sched_barrier(0);
}

// ------- transpose+convert W -> swizzled fragment-order bf16 panels ---------
__launch_bounds__(256)
__global__ void wcvt_kernel(const float* __restrict__ Wk, const float* __restrict__ Wv,
                            const float* __restrict__ Wq, u16* __restrict__ WTks,
                            u16* __restrict__ WTvs, u16* __restrict__ WTqs) {
  const float* in = blockIdx.z == 0 ? Wk : (blockIdx.z == 1 ? Wv : Wq);
  u16* out = blockIdx.z == 0 ? WTks : (blockIdx.z == 1 ? WTvs : WTqs);
  __shared__ float S[64][65];  // [k][col]
  const int t = threadIdx.x;
  const int k0 = blockIdx.y << 6, c0 = blockIdx.x << 6;
#pragma unroll
  for (int ii = 0; ii < 4; ++ii) {
    const int idx = t + ii * 256;
    const int r = idx >> 4, c4 = (idx & 15) << 2;
    const float4 v = *(const float4*)(in + (k0 + r) * D_MODEL + c0 + c4);
    S[r][c4] = v.x; S[r][c4 + 1] = v.y; S[r][c4 + 2] = v.z; S[r][c4 + 3] = v.w;
  }
  __syncthreads();
#pragma unroll
  for (int it = 0; it < 2; ++it) {
    const int fi = it * 256 + t;             // 0..511
    const int cb_loc = fi >> 7;              // 0..3
    const int ksm_loc = (fi >> 6) & 1;       // 0..1
    const int lane = fi & 63;
    const int col_loc = cb_loc * 16 + (lane & 15);
    const int kl0 = ksm_loc * 32 + (lane >> 4) * 8;
    union { bf16x8 v; u16 e[8]; } o;
#pragma unroll
    for (int jj = 0; jj < 8; ++jj) o.e[jj] = f2bf(S[kl0 + jj][col_loc]);
    const int cb16 = blockIdx.x * 4 + cb_loc;
    const int ksm = blockIdx.y * 2 + ksm_loc;
    *(bf16x8*)(out + cb16 * 8192 + ksm * 512 + lane * 8) = o.v;
  }
}

// ---------------- phase 1: [32][128] slices, depth-3 prefetch ---------------
// grid 1024: xc=f&7 (XCD), k=f>>3: rowgroup = xc*32 + (k>>2) in [0,256),
// hp = k&3. Block: 8 waves = 2 heads (hloc=w>>2) x 4 col-quarters (cq=w&3);
// 16 slices of [32 rows][128 k] (4 chunks x 4), double-buffered LDS,
// 3 rotating register prefetch sets.
__launch_bounds__(512, 2)
__global__ void phase1_kernel(const float* __restrict__ key, const float* __restrict__ value,
                              const u16* __restrict__ WTks, const u16* __restrict__ WTvs,
                              const float* __restrict__ bkp, const float* __restrict__ bvp,
                              float* __restrict__ part, float* __restrict__ sums) {
  __shared__ __align__(16) u16 smem[24576];  // 48KB
  u16* KA = smem;            // [2 buf][32 n][128 k], rows 256B, swz mask 7 (16KB)
  u16* VA = smem + 8192;     // (16KB)
  u16* ET = smem + 16384;    // [2 hloc][64 d][32 n], rows 64B, swz mask 3 (8KB)
  u16* VT = smem + 20480;    // (8KB)
  const int t = threadIdx.x;
  const int lane = t & 63, w = t >> 6;
  const int g = lane >> 4, lc = lane & 15;
  const int f = blockIdx.x;
  const int xc = f & 7, kk2 = f >> 3;
  const int rowgroup = xc * 32 + (kk2 >> 2);   // 0..255
  const int hp = kk2 & 3;
  const int hloc = w >> 2, cq = w & 3;
  const int h = hp * 2 + hloc;
  const int dl = cq * 16 + lc;
  const int b = rowgroup >> 7, grpl = rowgroup & 127;
  const int bh = b * 8 + h;
  u16* ETh = ET + hloc * 2048;
  u16* VTh = VT + hloc * 2048;
  const u16* wtkb = WTks + (h * 4 + cq) * 8192;
  const u16* wtvb = WTvs + (h * 4 + cq) * 8192;
  const float bbk = bkp[h * 64 + dl];
  const float bbv = bvp[h * 64 + dl];
  const int sr = t >> 4;                 // staging row 0..31
  const int sc = t & 15;                 // staging col-octet (8 f32)
  const int swoff = sr * 256 + ((sc * 16) ^ ((sr & 7) << 4));

  f32x4 pacc[4];
#pragma unroll
  for (int em = 0; em < 4; ++em) pacc[em] = (f32x4){0.f, 0.f, 0.f, 0.f};
  float sp = 0.f;
  f32x4 aK0 = (f32x4){0.f,0.f,0.f,0.f}, aK1 = aK0, aV0 = aK0, aV1 = aK0;

  float4 kreg[3][2], vreg[3][2];   // depth-3 rotating prefetch sets
  auto LOADSL = [&](int set, int gs) {    // called with compile-time args
    const int row = (rowgroup * 4 + (gs >> 2)) * 32 + sr;
    const float* kp = key + (size_t)row * D_MODEL + (gs & 3) * 128 + sc * 8;
    kreg[set][0] = *(const float4*)kp; kreg[set][1] = *(const float4*)(kp + 4);
    const float* vp = value + (size_t)row * D_MODEL + (gs & 3) * 128 + sc * 8;
    vreg[set][0] = *(const float4*)vp; vreg[set][1] = *(const float4*)(vp + 4);
  };
  auto WRITESL = [&](int set, int buf) {
    const float4 k0 = kreg[set][0], k1 = kreg[set][1];
    uint4 wk; wk.x = pk2(k0.x, k0.y); wk.y = pk2(k0.z, k0.w);
    wk.z = pk2(k1.x, k1.y); wk.w = pk2(k1.z, k1.w);
    *(uint4*)((char*)KA + buf * 8192 + swoff) = wk;
    const float4 v0 = vreg[set][0], v1 = vreg[set][1];
    uint4 wv; wv.x = pk2(v0.x, v0.y); wv.y = pk2(v0.z, v0.w);
    wv.z = pk2(v1.x, v1.y); wv.w = pk2(v1.z, v1.w);
    *(uint4*)((char*)VA + buf * 8192 + swoff) = wv;
  };

  // prologue: slices 0,1,2 in flight; slice 0 -> buf0
  LOADSL(0, 0);
  LOADSL(1, 1);
  LOADSL(2, 2);
  WRITESL(0, 0);
  bar_lgkm();

#pragma unroll
  for (int gs = 0; gs < 16; ++gs) {
    // ---- B-frag panels for this slice (L2), issued first ----
    bf16x8 bK[4], bV[4];
#pragma unroll
    for (int j = 0; j < 4; ++j) {
      const int ksm = (gs & 3) * 4 + j;
      bK[j] = *(const bf16x8*)(wtkb + ksm * 512 + lane * 8);
      bV[j] = *(const bf16x8*)(wtvb + ksm * 512 + lane * 8);
    }
    // ---- write slice gs+1 (loaded 2 slice-periods ago: no vmcnt stall) ----
    if (gs + 1 < 16) WRITESL((gs + 1) % 3, (gs + 1) & 1);
    // ---- refill freed set with slice gs+3 ----
    if (gs + 3 < 16) LOADSL(gs % 3, gs + 3);
    const u16* bufK = KA + (gs & 1) * 4096;
    const u16* bufV = VA + (gs & 1) * 4096;
    // ---- 4 k-steps of MFMA on slice gs ----
#pragma unroll
    for (int ksl = 0; ksl < 4; ++ksl) {
      const int kb = ksl * 64 + g * 16;
      bf16x8 a0 = ldsrd(bufK, lc, 256, kb, 7);
      bf16x8 a1 = ldsrd(bufK, 16 + lc, 256, kb, 7);
      aK0 = __builtin_amdgcn_mfma_f32_16x16x32_bf16(a0, bK[ksl], aK0, 0, 0, 0);
      aK1 = __builtin_amdgcn_mfma_f32_16x16x32_bf16(a1, bK[ksl], aK1, 0, 0, 0);
      bf16x8 c0 = ldsrd(bufV, lc, 256, kb, 7);
      bf16x8 c1 = ldsrd(bufV, 16 + lc, 256, kb, 7);
      aV0 = __builtin_amdgcn_mfma_f32_16x16x32_bf16(c0, bV[ksl], aV0, 0, 0, 0);
      aV1 = __builtin_amdgcn_mfma_f32_16x16x32_bf16(c1, bV[ksl], aV1, 0, 0, 0);
    }
    if ((gs & 3) == 3) {
      // ---- chunk epilogue (byte-identical math to R15, verified) ----
#pragma unroll
      for (int r = 0; r < 4; ++r) { aK0[r] = __expf(aK0[r] + bbk); sp += aK0[r]; }
#pragma unroll
      for (int r = 0; r < 4; ++r) { aK1[r] = __expf(aK1[r] + bbk); sp += aK1[r]; }
      *(uint2*)((char*)ETh + dl * 64 + ((g * 8) ^ ((dl & 3) << 4))) =
          make_uint2(pk2(aK0[0], aK0[1]), pk2(aK0[2], aK0[3]));
      *(uint2*)((char*)ETh + dl * 64 + ((32 + g * 8) ^ ((dl & 3) << 4))) =
          make_uint2(pk2(aK1[0], aK1[1]), pk2(aK1[2], aK1[3]));
      *(uint2*)((char*)VTh + dl * 64 + ((g * 8) ^ ((dl & 3) << 4))) =
          make_uint2(pk2(aV0[0] + bbv, aV0[1] + bbv), pk2(aV0[2] + bbv, aV0[3] + bbv));
      *(uint2*)((char*)VTh + dl * 64 + ((32 + g * 8) ^ ((dl & 3) << 4))) =
          make_uint2(pk2(aV1[0] + bbv, aV1[1] + bbv), pk2(aV1[2] + bbv, aV1[3] + bbv));
      bar_lgkm();  // ET/VT complete across the head's 4 waves
      {
        bf16x8 paf = ldsrd(ETh, dl, 64, g * 16, 3);
#pragma unroll
        for (int em = 0; em < 4; ++em) {
          bf16x8 pbf = ldsrd(VTh, em * 16 + lc, 64, g * 16, 3);
          pacc[em] = __builtin_amdgcn_mfma_f32_16x16x32_bf16(paf, pbf, pacc[em], 0, 0, 0);
        }
      }
      aK0 = (f32x4){0.f,0.f,0.f,0.f}; aK1 = aK0; aV0 = aK0; aV1 = aK0;
    }
    bar_lgkm();  // slice gs+1 visible; buf (gs&1) reads done; epilogue's
                 // ET/VT reads done before the next chunk's epilogue writes.
  }

  // ---- one store per block: f32 partials [e][d] + colsums ----
  float* pp = part + (size_t)(bh * 128 + grpl) * 4096;
#pragma unroll
  for (int em = 0; em < 4; ++em)
    *(f32x4*)(pp + (em * 16 + lc) * 64 + cq * 16 + g * 4) = pacc[em];
  sp += __shfl_xor(sp, 16); sp += __shfl_xor(sp, 32);
  if (g == 0) sums[(size_t)(bh * 128 + grpl) * 64 + dl] = sp;
}

// ---------------- phase 2: reduce partials -> ctx[d][e] ---------------------
__launch_bounds__(256)
__global__ void reduce_kernel(const float* __restrict__ part, const float* __restrict__ sums,
                              float* __restrict__ ctx) {
  __shared__ float den[64];
  const int bh = blockIdx.x;
  const int t = threadIdx.x;
  if (t < 64) {
    float s = 0.f;
    for (int gp = 0; gp < 128; ++gp) s += sums[(size_t)(bh * 128 + gp) * 64 + t];
    den[t] = s;
  }
  float4 A0 = {0,0,0,0}, A1 = {0,0,0,0}, A2 = {0,0,0,0}, A3 = {0,0,0,0};
  const float* pb = part + (size_t)bh * 128 * 4096;
  for (int gp = 0; gp < 128; ++gp) {
    const float4* q = (const float4*)(pb + gp * 4096 + t * 16);
    const float4 q0 = q[0], q1 = q[1], q2 = q[2], q3 = q[3];
    A0.x += q0.x; A0.y += q0.y; A0.z += q0.z; A0.w += q0.w;
    A1.x += q1.x; A1.y += q1.y; A1.z += q1.z; A1.w += q1.w;
    A2.x += q2.x; A2.y += q2.y; A2.z += q2.z; A2.w += q2.w;
    A3.x += q3.x; A3.y += q3.y; A3.z += q3.z; A3.w += q3.w;
  }
  __syncthreads();
  const int e = t >> 2, d0 = (t & 3) * 16;
  float* cb = ctx + (size_t)bh * 4096 + e;
  const float r0[4] = {A0.x, A0.y, A0.z, A0.w};
  const float r1[4] = {A1.x, A1.y, A1.z, A1.w};
  const float r2[4] = {A2.x, A2.y, A2.z, A2.w};
  const float r3[4] = {A3.x, A3.y, A3.z, A3.w};
#pragma unroll
  for (int i = 0; i < 4; ++i) cb[(d0 + i) * 64] = r0[i] / den[d0 + i];
#pragma unroll
  for (int i = 0; i < 4; ++i) cb[(d0 + 4 + i) * 64] = r1[i] / den[d0 + 4 + i];
#pragma unroll
  for (int i = 0; i < 4; ++i) cb[(d0 + 8 + i) * 64] = r2[i] / den[d0 + 8 + i];
#pragma unroll
  for (int i = 0; i < 4; ++i) cb[(d0 + 12 + i) * 64] = r3[i] / den[d0 + 12 + i];
}

// -------- MTs (swizzled) = (ctx_h @ Wo_h)^T per batch -----------------------
__launch_bounds__(256)
__global__ void mbigT_kernel(const float* __restrict__ ctx, const float* __restrict__ Wo,
                             u16* __restrict__ MTs) {
  __shared__ float Clds[64][65];
  __shared__ float Wlds2[64][64];
  const int t = threadIdx.x;
  const int tx = t & 15, ty = t >> 4;
  const int cc = blockIdx.x;
  const int bh = blockIdx.y;
  const int b = bh >> 3, h = bh & 7;
  const float* ch = ctx + bh * 4096;
  for (int i4 = t; i4 < 1024; i4 += 256) {
    const int r = i4 >> 4, c = (i4 & 15) << 2;
    const float4 v = *(const float4*)(ch + (r << 6) + c);
    Clds[r][c] = v.x; Clds[r][c + 1] = v.y; Clds[r][c + 2] = v.z; Clds[r][c + 3] = v.w;
    const float4 wv = *(const float4*)(Wo + (h * 64 + r) * D_MODEL + cc * 64 + c);
    Wlds2[r][c] = wv.x; Wlds2[r][c + 1] = wv.y; Wlds2[r][c + 2] = wv.z; Wlds2[r][c + 3] = wv.w;
  }
  __syncthreads();
  float acc[4][4] = {};
#pragma unroll 8
  for (int k = 0; k < 64; ++k) {
    float a[4], wv[4];
#pragma unroll
    for (int i = 0; i < 4; ++i) a[i] = Clds[(ty << 2) + i][k];
#pragma unroll
    for (int j = 0; j < 4; ++j) wv[j] = Wlds2[k][(tx << 2) + j];
#pragma unroll
    for (int i = 0; i < 4; ++i)
#pragma unroll
      for (int j = 0; j < 4; ++j) acc[i][j] = fmaf(a[i], wv[j], acc[i][j]);
  }
#pragma unroll
  for (int i = 0; i < 4; ++i)
#pragma unroll
    for (int j = 0; j < 4; ++j) {
      const int c = cc * 64 + (tx << 2) + j;
      const int k = h * 64 + (ty << 2) + i;
      const int cb16 = c >> 4, lcc = c & 15;
      const int ksm = k >> 5, gg = (k >> 3) & 3, jb = k & 7;
      MTs[(size_t)b * 262144 + cb16 * 8192 + ksm * 512 + (gg * 16 + lcc) * 8 + jb]
          = f2bf(acc[i][j]);
    }
}

// ---------------- phase 3: [32][128] Q slices + softmax + out-GEMM ----------
__launch_bounds__(512, 2)
__global__ void phase3_kernel(const float* __restrict__ query, const u16* __restrict__ WTqs,
                              const float* __restrict__ bqp, const u16* __restrict__ MTs,
                              const float* __restrict__ bop, float* __restrict__ out) {
  __shared__ __align__(16) u16 smem[24576];  // 48KB
  u16* SL = smem;          // [2 buf][32 n][128 k], rows 256B, swz mask 7 (16KB)
  u16* P  = smem + 8192;   // [32 n][512 d], rows 1024B, swz mask 7 (32KB)
  const int t = threadIdx.x;
  const int lane = t & 63, w = t >> 6;
  const int g = lane >> 4, lc = lane & 15;
  const int chunk = blockIdx.x;
  const int n0 = chunk * 32;
  const int b = chunk >> 9;
  const int c0 = w * 64;
  const int sr = t >> 4;
  const int sc = t & 15;
  const int swoff = sr * 256 + ((sc * 16) ^ ((sr & 7) << 4));

  f32x4 acc[4][2];
#pragma unroll
  for (int m = 0; m < 4; ++m)
#pragma unroll
    for (int n = 0; n < 2; ++n) acc[m][n] = (f32x4){0.f, 0.f, 0.f, 0.f};

  float4 qreg[3][2];   // depth-3 rotating prefetch
  auto LOADQ = [&](int set, int gs) {
    const float* qp = query + (size_t)(n0 + sr) * D_MODEL + gs * 128 + sc * 8;
    qreg[set][0] = *(const float4*)qp; qreg[set][1] = *(const float4*)(qp + 4);
  };
  auto WRITEQ = [&](int set, int buf) {
    const float4 q0 = qreg[set][0], q1 = qreg[set][1];
    uint4 wq; wq.x = pk2(q0.x, q0.y); wq.y = pk2(q0.z, q0.w);
    wq.z = pk2(q1.x, q1.y); wq.w = pk2(q1.z, q1.w);
    *(uint4*)((char*)SL + buf * 8192 + swoff) = wq;
  };

  LOADQ(0, 0); LOADQ(1, 1); LOADQ(2, 2);
  WRITEQ(0, 0);
  bar_lgkm();

#pragma unroll
  for (int gs = 0; gs < 4; ++gs) {
    if (gs + 1 < 4) WRITEQ((gs + 1) % 3, (gs + 1) & 1);
    if (gs + 3 < 4) LOADQ(gs % 3, gs + 3);
    const u16* S = SL + (gs & 1) * 4096;
#pragma unroll
    for (int ksl = 0; ksl < 4; ++ksl) {
      const int ksm = gs * 4 + ksl;
      bf16x8 af[4], bfr[2];
#pragma unroll
      for (int mf = 0; mf < 4; ++mf)
        af[mf] = *(const bf16x8*)(WTqs + (w * 4 + mf) * 8192 + ksm * 512 + lane * 8);
      const int kb = ksl * 64 + g * 16;
#pragma unroll
      for (int nf = 0; nf < 2; ++nf) bfr[nf] = ldsrd(S, nf * 16 + lc, 256, kb, 7);
#pragma unroll
      for (int mf = 0; mf < 4; ++mf)
#pragma unroll
        for (int nf = 0; nf < 2; ++nf)
          acc[mf][nf] = __builtin_amdgcn_mfma_f32_16x16x32_bf16(af[mf], bfr[nf], acc[mf][nf], 0, 0, 0);
    }
    bar_lgkm();
  }
  // ---- softmax over d (per n), *1/8, bf16 -> P ----
  {
    float bqv[4][4];
#pragma unroll
    for (int m = 0; m < 4; ++m)
#pragma unroll
      for (int r = 0; r < 4; ++r) bqv[m][r] = bqp[c0 + m * 16 + g * 4 + r];
#pragma unroll
    for (int nf = 0; nf < 2; ++nf) {
      float mx = -3.0e38f;
#pragma unroll
      for (int m = 0; m < 4; ++m)
#pragma unroll
        for (int r = 0; r < 4; ++r) {
          const float v = acc[m][nf][r] + bqv[m][r];
          acc[m][nf][r] = v; mx = fmaxf(mx, v);
        }
      mx = fmaxf(mx, __shfl_xor(mx, 16)); mx = fmaxf(mx, __shfl_xor(mx, 32));
      float s = 0.f;
#pragma unroll
      for (int m = 0; m < 4; ++m)
#pragma unroll
        for (int r = 0; r < 4; ++r) {
          const float e = __expf(acc[m][nf][r] - mx);
          acc[m][nf][r] = e; s += e;
        }
      s += __shfl_xor(s, 16); s += __shfl_xor(s, 32);
      const float fsc = 0.125f / s;
      const int n = nf * 16 + lc;
#pragma unroll
      for (int m = 0; m < 4; ++m) {
        const uint2 pw = make_uint2(pk2(acc[m][nf][0] * fsc, acc[m][nf][1] * fsc),
                                    pk2(acc[m][nf][2] * fsc, acc[m][nf][3] * fsc));
        *(uint2*)((char*)P + n * 1024 + ((w * 128 + m * 32 + g * 8) ^ ((n & 7) << 4))) = pw;
      }
    }
  }
  bar_lgkm();
  // ---- out^T = Mbig^T[b] @ P^T ----
  f32x4 oc[4][2];
#pragma unroll
  for (int m = 0; m < 4; ++m)
#pragma unroll
    for (int n = 0; n < 2; ++n) oc[m][n] = (f32x4){0.f, 0.f, 0.f, 0.f};
  const u16* MT = MTs + (size_t)b * 262144;
#pragma unroll 2
  for (int ks = 0; ks < 16; ++ks) {
    bf16x8 af[4], bfr[2];
#pragma unroll
    for (int mf = 0; mf < 4; ++mf)
      af[mf] = *(const bf16x8*)(MT + (w * 4 + mf) * 8192 + ks * 512 + lane * 8);
#pragma unroll
    for (int nf = 0; nf < 2; ++nf) bfr[nf] = ldsrd(P, nf * 16 + lc, 1024, ks * 64 + g * 16, 7);
#pragma unroll
    for (int mf = 0; mf < 4; ++mf)
#pragma unroll
      for (int nf = 0; nf < 2; ++nf)
        oc[mf][nf] = __builtin_amdgcn_mfma_f32_16x16x32_bf16(af[mf], bfr[nf], oc[mf][nf], 0, 0, 0);
  }
  {
    float bov[4][4];
#pragma unroll
    for (int m = 0; m < 4; ++m)
#pragma unroll
      for (int r = 0; r < 4; ++r) bov[m][r] = bop[c0 + m * 16 + g * 4 + r];
#pragma unroll
    for (int mf = 0; mf < 4; ++mf)
#pragma unroll
      for (int nf = 0; nf < 2; ++nf) {
        float4 o;
        o.x = oc[mf][nf][0] + bov[mf][0]; o.y = oc[mf][nf][1] + bov[mf][1];
        o.z = oc[mf][nf][2] + bov[mf][2]; o.w = oc[mf][nf][3] + bov[mf][3];
        *(float4*)(out + (size_t)(n0 + nf * 16 + lc) * D_MODEL + c0 + mf * 16 + g * 4) = o;
      }
  }
}

__global__ void sentinel_kernel(float* out) { out[0] = 1.0e9f; }

extern "C" void kernel_launch(void* const* d_in, const int* in_sizes, int n_in,
                              void* d_out, int out_size, void* d_ws, size_t ws_size,
                              hipStream_t stream) {
  const float* query = (const float*)d_in[0];
  const float* key   = (const float*)d_in[1];
  const float* value = (const float*)d_in[2];
  const float* Wq = (const float*)d_in[3];
  const float* bq = (const float*)d_in[4];
  const float* Wk = (const float*)d_in[5];
  const float* bk = (const float*)d_in[6];
  const float* Wv = (const float*)d_in[7];
  const float* bv = (const float*)d_in[8];
  const float* Wo = (const float*)d_in[9];
  const float* bo = (const float*)d_in[10];
  float* out = (float*)d_out;
  char* ws = (char*)d_ws;

  if (ws_size < (size_t)WS_NEEDED) {
    sentinel_kernel<<<1, 1, 0, stream>>>(out);
    return;
  }

  float* part = (float*)(ws + PART_OFF);
  float* sums = (float*)(ws + SUMS_OFF);
  float* ctx  = (float*)(ws + CTX_OFF);
  u16* WTks   = (u16*)(ws + WTKS_OFF);
  u16* WTvs   = (u16*)(ws + WTVS_OFF);
  u16* WTqs   = (u16*)(ws + WTQS_OFF);
  u16* MTs    = (u16*)(ws + MTS_OFF);

  const dim3 blk256(256);
  wcvt_kernel<<<dim3(8, 8, 3), blk256, 0, stream>>>(Wk, Wv, Wq, WTks, WTvs, WTqs);
  phase1_kernel<<<1024, 512, 0, stream>>>(key, value, WTks, WTvs, bk, bv, part, sums);
  reduce_kernel<<<16, blk256, 0, stream>>>(part, sums, ctx);
  mbigT_kernel<<<dim3(8, 16), blk256, 0, stream>>>(ctx, Wo, MTs);
  phase3_kernel<<<1024, 512, 0, stream>>>(query, WTqs, bq, MTs, bo, out);
}